// Round 15
// baseline (151.146 us; speedup 1.0000x reference)
//
#include <hip/hip_runtime.h>
#include <math.h>

#define N_ENT 50000
#define N_REL 500
#define DEG 32
#define TOPK 10
#define H_DIM 256
#define N_HEADS 4
#define HEAD_DIM 64

typedef __attribute__((ext_vector_type(8))) short short8v;
typedef __attribute__((ext_vector_type(4))) float f32x4;

// ---------------- workspace layout (bytes) ----------------
constexpr size_t OFF_SSRC0 = 0;                      // f64 [N_ENT]
constexpr size_t OFF_SR0   = 400000;                 // f64 [N_REL]
constexpr size_t OFF_U0    = 404000;                 // f64 [256]
constexpr size_t OFF_V0    = 406048;                 // f64 [256]
constexpr size_t OFF_SS    = 408096;                 // f32 [N_ENT][8]
constexpr size_t OFF_SSR   = 2008096;                // f32 [N_REL][8]
constexpr size_t OFF_U8    = 2024096;                // f32 [256][8]
constexpr size_t OFF_V8    = 2032288;                // f32 [256][8]
constexpr size_t OFF_B1H   = 2040480;                // bf16 packed 131072 B each
constexpr size_t OFF_B2H   = 2302624;
constexpr size_t OFF_B3H   = 2564768;
constexpr size_t OFF_RPK   = 2826912;                // bf16 row-major rel rows [512][256]
constexpr size_t OFF_EAH   = 3089056;                // bf16 row-major A (ent; later neigh) [50048][256]
constexpr size_t OFF_EMBBF = 28713632;               // bf16 [N_ENT][256] emb_t (row-major)
constexpr size_t OFF_RELBF = 54313632;               // bf16 [N_REL][256]
constexpr size_t WS_NEED   = 54569632;               // ~52 MB

__device__ __forceinline__ float leaky(float x) { return x >= 0.f ? x : 0.2f * x; }

__device__ __forceinline__ unsigned short bf16_rne(float x) {
    unsigned int u = __float_as_uint(x);
    unsigned int r = u + 0x7fffu + ((u >> 16) & 1u);
    return (unsigned short)(r >> 16);
}
__device__ __forceinline__ float bf2f(unsigned short x) {
    return __uint_as_float((unsigned)x << 16);
}

// B-side MFMA-fragment pack offset
__device__ __forceinline__ size_t pack_off(int row, int d) {
    return ((size_t)(row >> 4) * 8 + (d >> 5)) * 512 +
           (((d >> 3) & 3) * 16 + (row & 15)) * 8 + (d & 7);
}

// ---------------- K0: setup (U/V vectors | B splits) ----------------
__global__ __launch_bounds__(256) void setup_kernel(
    const float* __restrict__ W, const float* __restrict__ W_r,
    const float* __restrict__ a, const float* __restrict__ nw,
    float* __restrict__ U8, double* __restrict__ u0,
    float* __restrict__ V8, double* __restrict__ v0,
    unsigned short* __restrict__ b1h, unsigned short* __restrict__ b2h,
    unsigned short* __restrict__ b3h)
{
    const int bid = blockIdx.x;
    const int tid = threadIdx.x;
    if (bid == 0) {
        int d = tid;
        #pragma unroll
        for (int h = 0; h < N_HEADS; ++h) {
            float ss = 0.f, sd = 0.f;
            #pragma unroll
            for (int e = 0; e < HEAD_DIM; ++e) {
                float w = W[h * 16384 + d * 64 + e];
                ss += w * a[h * 192 + e];
                sd += w * a[h * 192 + 64 + e];
            }
            U8[d * 8 + h] = ss;
            U8[d * 8 + 4 + h] = sd;
        }
        double s0 = 0.0;
        #pragma unroll
        for (int e = 0; e < HEAD_DIM; ++e)
            s0 += (double)W[d * 64 + e] * (double)a[e];
        u0[d] = s0;
    } else if (bid == 1) {
        int d = tid;
        #pragma unroll
        for (int h = 0; h < N_HEADS; ++h) {
            float sv = 0.f;
            #pragma unroll
            for (int e = 0; e < HEAD_DIM; ++e)
                sv += W_r[h * 16384 + d * 64 + e] * a[h * 192 + 128 + e];
            V8[d * 8 + h] = sv;
            V8[d * 8 + 4 + h] = 0.f;
        }
        double s0 = 0.0;
        #pragma unroll
        for (int e = 0; e < HEAD_DIM; ++e)
            s0 += (double)W_r[d * 64 + e] * (double)a[128 + e];
        v0[d] = s0;
    } else {
        int n = bid - 2;
        int k = tid;
        int h = n >> 6, e = n & 63;
        float x1 = W[h * 16384 + k * 64 + e];
        float x2 = nw[k * 256 + n];
        float x3 = W_r[h * 16384 + k * 64 + e];
        size_t off = pack_off(n, k);
        b1h[off] = bf16_rne(x1);
        b2h[off] = bf16_rne(x2);
        b3h[off] = bf16_rne(x3);
    }
}

// ---------------- K1: rank-1 scores + row-major bf16 split (w/ prefetch) ----------------
__global__ __launch_bounds__(256) void ss_kernel(
    const float* __restrict__ ent, const float* __restrict__ relm,
    const float* __restrict__ U8, const double* __restrict__ u0,
    const float* __restrict__ V8, const double* __restrict__ v0,
    float* __restrict__ SS, double* __restrict__ ssrc0, unsigned short* __restrict__ apk,
    float* __restrict__ SSR, double* __restrict__ sr0, unsigned short* __restrict__ rpk)
{
    const int tid = threadIdx.x;
    const int l = tid & 63;
    const int el = l & 31;
    const int q2 = l >> 5;

    const bool isent = blockIdx.x < 2048;
    const float* X = isent ? ent : relm;
    const float* U8v = isent ? U8 : V8;
    const double* u0v = isent ? u0 : v0;
    float* SSout = isent ? SS : SSR;
    double* s0out = isent ? ssrc0 : sr0;
    unsigned short* Xpk = isent ? apk : rpk;
    const int N = isent ? N_ENT : N_REL;
    const int wave0 = isent ? ((blockIdx.x * 256 + tid) >> 6)
                            : (((blockIdx.x - 2048) * 256 + tid) >> 6);
    const int nwaves = isent ? 8192 : 252;

    float uu[8][8];
    #pragma unroll
    for (int i = 0; i < 8; ++i) {
        float4 a4 = *(const float4*)(U8v + (el * 8 + i) * 8);
        float4 b4 = *(const float4*)(U8v + (el * 8 + i) * 8 + 4);
        uu[i][0] = a4.x; uu[i][1] = a4.y; uu[i][2] = a4.z; uu[i][3] = a4.w;
        uu[i][4] = b4.x; uu[i][5] = b4.y; uu[i][6] = b4.z; uu[i][7] = b4.w;
    }
    double ud[8];
    #pragma unroll
    for (int i = 0; i < 8; ++i) ud[i] = u0v[el * 8 + i];

    const int jout = ((el & 1) << 2) | (el & 2) | ((el >> 2) & 1);
    const int half = N / 2;

    int p = wave0;
    float4 x1, x2;
    if (p < half) {
        int n0 = p * 2 + q2;
        x1 = *(const float4*)(X + (size_t)n0 * 256 + el * 8);
        x2 = *(const float4*)(X + (size_t)n0 * 256 + el * 8 + 4);
    }
    for (; p < half; p += nwaves) {
        const int n = p * 2 + q2;
        const float4 cx1 = x1, cx2 = x2;
        const int np = p + nwaves;
        if (np < half) {
            int n1 = np * 2 + q2;
            x1 = *(const float4*)(X + (size_t)n1 * 256 + el * 8);
            x2 = *(const float4*)(X + (size_t)n1 * 256 + el * 8 + 4);
        }
        float xs[8] = {cx1.x, cx1.y, cx1.z, cx1.w, cx2.x, cx2.y, cx2.z, cx2.w};

        short8v ov;
        #pragma unroll
        for (int i = 0; i < 8; ++i) ov[i] = (short)bf16_rne(xs[i]);
        *(short8v*)(Xpk + (size_t)n * 256 + el * 8) = ov;

        float pj[8] = {0.f, 0.f, 0.f, 0.f, 0.f, 0.f, 0.f, 0.f};
        double pd = 0.0;
        #pragma unroll
        for (int i = 0; i < 8; ++i) {
            #pragma unroll
            for (int j = 0; j < 8; ++j) pj[j] += xs[i] * uu[i][j];
            pd += (double)xs[i] * ud[i];
        }

        const bool b1 = (el & 1);
        float q[4];
        #pragma unroll
        for (int j = 0; j < 4; ++j) {
            float mine = b1 ? pj[j + 4] : pj[j];
            float send = b1 ? pj[j] : pj[j + 4];
            q[j] = mine + __shfl_xor(send, 1);
        }
        const bool b2 = (el & 2);
        float r2[2];
        #pragma unroll
        for (int j = 0; j < 2; ++j) {
            float mine = b2 ? q[j + 2] : q[j];
            float send = b2 ? q[j] : q[j + 2];
            r2[j] = mine + __shfl_xor(send, 2);
        }
        const bool b4 = (el & 4);
        {
            float mine = b4 ? r2[1] : r2[0];
            float send = b4 ? r2[0] : r2[1];
            r2[0] = mine + __shfl_xor(send, 4);
        }
        r2[0] += __shfl_xor(r2[0], 8);
        r2[0] += __shfl_xor(r2[0], 16);

        #pragma unroll
        for (int off = 1; off < 32; off <<= 1) pd += __shfl_xor(pd, off);

        if (el < 8) SSout[(size_t)n * 8 + jout] = r2[0];
        if (el == 0) s0out[n] = pd;
    }
}

// ---------------- K2: MFMA GEMM, row-major A staged to LDS, B hi packed, bf16 out ----------------
__global__ __launch_bounds__(256, 4) void gemm_hi(
    const unsigned short* __restrict__ A1, const unsigned short* __restrict__ B1,
    unsigned short* __restrict__ C1, int M1, int nb1,
    const unsigned short* __restrict__ A2, const unsigned short* __restrict__ B2,
    unsigned short* __restrict__ C2, int M2)
{
    __shared__ unsigned short As[64][264];

    const int tid = threadIdx.x;
    const int l = tid & 63;
    const int w = tid >> 6;
    const int rl = l & 15;
    const int ql = l >> 4;

    const int b = blockIdx.x;
    const unsigned short* A = (b < nb1) ? A1 : A2;
    const unsigned short* Bh = (b < nb1) ? B1 : B2;
    unsigned short* C       = (b < nb1) ? C1 : C2;
    const int M             = (b < nb1) ? M1 : M2;
    const int bm            = ((b < nb1) ? b : (b - nb1)) * 64;

    const unsigned short* Ag = A + (size_t)bm * 256;
    #pragma unroll
    for (int i = 0; i < 8; ++i) {
        int u = i * 256 + tid;
        short8v v = *(const short8v*)(Ag + (size_t)u * 8);
        *(short8v*)&As[u >> 5][(u & 31) * 8] = v;
    }
    __syncthreads();

    const unsigned short* bhb = Bh + (size_t)w * 16384 + l * 8;

    f32x4 acc[4][4];
    #pragma unroll
    for (int i = 0; i < 4; ++i)
        #pragma unroll
        for (int j = 0; j < 4; ++j) acc[i][j] = (f32x4){0.f, 0.f, 0.f, 0.f};

    #pragma unroll
    for (int ks = 0; ks < 8; ++ks) {
        short8v ah[4], bh[4];
        #pragma unroll
        for (int mf = 0; mf < 4; ++mf)
            ah[mf] = *(const short8v*)&As[mf * 16 + rl][ks * 32 + ql * 8];
        #pragma unroll
        for (int nf = 0; nf < 4; ++nf)
            bh[nf] = *(const short8v*)(bhb + nf * 4096 + ks * 512);
        #pragma unroll
        for (int mf = 0; mf < 4; ++mf)
            #pragma unroll
            for (int nf = 0; nf < 4; ++nf)
                acc[mf][nf] = __builtin_amdgcn_mfma_f32_16x16x32_bf16(ah[mf], bh[nf], acc[mf][nf], 0, 0, 0);
    }

    #pragma unroll
    for (int mf = 0; mf < 4; ++mf) {
        int row0 = bm + mf * 16 + ql * 4;
        #pragma unroll
        for (int nf = 0; nf < 4; ++nf) {
            int c = w * 64 + nf * 16 + rl;
            #pragma unroll
            for (int j = 0; j < 4; ++j) {
                int r = row0 + j;
                if (r < M)
                    C[(size_t)r * 256 + c] = bf16_rne(acc[mf][nf][j]);
            }
        }
    }
}

// ---------------- K3: fused select+softmax+aggregate, 2-phase pipelined ----------------
// 32 lanes per node; each wave handles 2 phases x 2 nodes = 16 nodes/block.
// All select global loads issued before any gathers (so their waits never drain
// the gather queue); select1 hides gathers0 latency; FMA0 hides gathers1.
__global__ __launch_bounds__(256, 2) void node_kernel(
    const int* __restrict__ src, const int* __restrict__ relid,
    const float* __restrict__ SS, const double* __restrict__ ssrc0,
    const float* __restrict__ SSR, const double* __restrict__ sr0,
    const unsigned short* __restrict__ emb_bf, const unsigned short* __restrict__ rel_bf,
    unsigned short* __restrict__ napk)
{
    __shared__ double scs[8][33];
    __shared__ unsigned idsS[2][8][12];
    __shared__ float wtsS[2][8][10][4];
    __shared__ float sumsS[2][8][4];

    const int tid = threadIdx.x;
    const int l = tid & 63;
    const int el = l & 31;
    const int hb = l & 32;
    const int nib = tid >> 5;
    const int n0 = blockIdx.x * 16 + nib;
    const int n1 = blockIdx.x * 16 + 8 + nib;
    const int h = el >> 3;

    // ---- all select loads up front (both phases) ----
    const int sd0 = src[n0 * DEG + el], rd0 = relid[n0 * DEG + el];
    const int sd1 = src[n1 * DEG + el], rd1 = relid[n1 * DEG + el];
    const double sa0 = ssrc0[sd0], sb0 = sr0[rd0];
    const double sa1 = ssrc0[sd1], sb1 = sr0[rd1];
    const float4 ssv0 = *(const float4*)(SS + (size_t)sd0 * 8);
    const float4 srv0 = *(const float4*)(SSR + (size_t)rd0 * 8);
    const float4 sdv0 = *(const float4*)(SS + (size_t)n0 * 8 + 4);
    const float4 ssv1 = *(const float4*)(SS + (size_t)sd1 * 8);
    const float4 srv1 = *(const float4*)(SSR + (size_t)rd1 * 8);
    const float4 sdv1 = *(const float4*)(SS + (size_t)n1 * 8 + 4);

    // ---- select phase 0 ----
    const double sc0 = sa0 + sb0;
    scs[nib][el] = sc0;
    int cnt0 = 0;
    #pragma unroll
    for (int j = 0; j < DEG; ++j) {
        double sj = scs[nib][j];
        cnt0 += (sj > sc0 || (sj == sc0 && j < el)) ? 1 : 0;
    }
    const bool sel0 = (cnt0 < TOPK);
    const unsigned mask0 = (unsigned)(__ballot(sel0) >> hb);
    const int pos0 = __popc(mask0 & ((1u << el) - 1u));
    float ex0 = __expf(leaky(ssv0.x + sdv0.x + srv0.x));
    float ey0 = __expf(leaky(ssv0.y + sdv0.y + srv0.y));
    float ez0 = __expf(leaky(ssv0.z + sdv0.z + srv0.z));
    float ew0 = __expf(leaky(ssv0.w + sdv0.w + srv0.w));
    if (!sel0) { ex0 = 0.f; ey0 = 0.f; ez0 = 0.f; ew0 = 0.f; }
    if (sel0) {
        idsS[0][nib][pos0] = (unsigned)sd0 | ((unsigned)rd0 << 16);
        float4 wv; wv.x = ex0; wv.y = ey0; wv.z = ez0; wv.w = ew0;
        *(float4*)&wtsS[0][nib][pos0][0] = wv;
    }
    {
        const bool b1 = (el & 1);
        float p0 = (b1 ? ez0 : ex0) + __shfl_xor(b1 ? ex0 : ez0, 1);
        float p1 = (b1 ? ew0 : ey0) + __shfl_xor(b1 ? ey0 : ew0, 1);
        const bool b2 = (el & 2);
        float qsum = (b2 ? p1 : p0) + __shfl_xor(b2 ? p0 : p1, 2);
        qsum += __shfl_xor(qsum, 4);
        qsum += __shfl_xor(qsum, 8);
        qsum += __shfl_xor(qsum, 16);
        if (el < 4) sumsS[0][nib][((el & 1) << 1) | ((el >> 1) & 1)] = qsum;
    }

    // ---- issue gathers for phase 0 ----
    int sk0[TOPK], rk0[TOPK];
    #pragma unroll
    for (int k = 0; k < TOPK; ++k) {
        unsigned idk = idsS[0][nib][k];
        sk0[k] = (int)(idk & 0xFFFFu);
        rk0[k] = (int)(idk >> 16);
    }
    short8v ev0[TOPK], rv0[TOPK];
    #pragma unroll
    for (int k = 0; k < TOPK; ++k)
        ev0[k] = *(const short8v*)(emb_bf + (size_t)sk0[k] * 256 + el * 8);
    #pragma unroll
    for (int k = 0; k < TOPK; ++k)
        rv0[k] = *(const short8v*)(rel_bf + (size_t)rk0[k] * 256 + el * 8);

    // ---- select phase 1 (overlaps gathers0 latency) ----
    const double sc1 = sa1 + sb1;
    scs[nib][el] = sc1;
    int cnt1 = 0;
    #pragma unroll
    for (int j = 0; j < DEG; ++j) {
        double sj = scs[nib][j];
        cnt1 += (sj > sc1 || (sj == sc1 && j < el)) ? 1 : 0;
    }
    const bool sel1 = (cnt1 < TOPK);
    const unsigned mask1 = (unsigned)(__ballot(sel1) >> hb);
    const int pos1 = __popc(mask1 & ((1u << el) - 1u));
    float ex1 = __expf(leaky(ssv1.x + sdv1.x + srv1.x));
    float ey1 = __expf(leaky(ssv1.y + sdv1.y + srv1.y));
    float ez1 = __expf(leaky(ssv1.z + sdv1.z + srv1.z));
    float ew1 = __expf(leaky(ssv1.w + sdv1.w + srv1.w));
    if (!sel1) { ex1 = 0.f; ey1 = 0.f; ez1 = 0.f; ew1 = 0.f; }
    if (sel1) {
        idsS[1][nib][pos1] = (unsigned)sd1 | ((unsigned)rd1 << 16);
        float4 wv; wv.x = ex1; wv.y = ey1; wv.z = ez1; wv.w = ew1;
        *(float4*)&wtsS[1][nib][pos1][0] = wv;
    }
    {
        const bool b1 = (el & 1);
        float p0 = (b1 ? ez1 : ex1) + __shfl_xor(b1 ? ex1 : ez1, 1);
        float p1 = (b1 ? ew1 : ey1) + __shfl_xor(b1 ? ey1 : ew1, 1);
        const bool b2 = (el & 2);
        float qsum = (b2 ? p1 : p0) + __shfl_xor(b2 ? p0 : p1, 2);
        qsum += __shfl_xor(qsum, 4);
        qsum += __shfl_xor(qsum, 8);
        qsum += __shfl_xor(qsum, 16);
        if (el < 4) sumsS[1][nib][((el & 1) << 1) | ((el >> 1) & 1)] = qsum;
    }

    // ---- issue gathers for phase 1 ----
    int sk1[TOPK], rk1[TOPK];
    #pragma unroll
    for (int k = 0; k < TOPK; ++k) {
        unsigned idk = idsS[1][nib][k];
        sk1[k] = (int)(idk & 0xFFFFu);
        rk1[k] = (int)(idk >> 16);
    }
    short8v ev1[TOPK], rv1[TOPK];
    #pragma unroll
    for (int k = 0; k < TOPK; ++k)
        ev1[k] = *(const short8v*)(emb_bf + (size_t)sk1[k] * 256 + el * 8);
    #pragma unroll
    for (int k = 0; k < TOPK; ++k)
        rv1[k] = *(const short8v*)(rel_bf + (size_t)rk1[k] * 256 + el * 8);

    // ---- FMA + store phase 0 (overlaps gathers1 latency) ----
    {
        const float rsh = 1.f / sumsS[0][nib][h];
        float acc[8] = {0.f, 0.f, 0.f, 0.f, 0.f, 0.f, 0.f, 0.f};
        #pragma unroll
        for (int k = 0; k < TOPK; ++k) {
            float w = wtsS[0][nib][k][h] * rsh;
            #pragma unroll
            for (int j = 0; j < 8; ++j)
                acc[j] += w * (bf2f((unsigned short)ev0[k][j]) + bf2f((unsigned short)rv0[k][j]));
        }
        short8v ov;
        #pragma unroll
        for (int j = 0; j < 8; ++j) ov[j] = (short)bf16_rne(acc[j]);
        *(short8v*)(napk + (size_t)n0 * 256 + el * 8) = ov;
    }

    // ---- FMA + store phase 1 ----
    {
        const float rsh = 1.f / sumsS[1][nib][h];
        float acc[8] = {0.f, 0.f, 0.f, 0.f, 0.f, 0.f, 0.f, 0.f};
        #pragma unroll
        for (int k = 0; k < TOPK; ++k) {
            float w = wtsS[1][nib][k][h] * rsh;
            #pragma unroll
            for (int j = 0; j < 8; ++j)
                acc[j] += w * (bf2f((unsigned short)ev1[k][j]) + bf2f((unsigned short)rv1[k][j]));
        }
        short8v ov;
        #pragma unroll
        for (int j = 0; j < 8; ++j) ov[j] = (short)bf16_rne(acc[j]);
        *(short8v*)(napk + (size_t)n1 * 256 + el * 8) = ov;
    }
}

// ---------------- K4: MFMA GEMM, row-major A staged to LDS, B hi packed, f32 tanh out ----------------
__global__ __launch_bounds__(256, 4) void gemm_out(
    const unsigned short* __restrict__ A, const unsigned short* __restrict__ Bpkh,
    float* __restrict__ Cout, int M)
{
    __shared__ unsigned short As[64][264];

    const int tid = threadIdx.x;
    const int l = tid & 63;
    const int w = tid >> 6;
    const int bm = blockIdx.x * 64;
    const int rl = l & 15;
    const int ql = l >> 4;

    const unsigned short* Ag = A + (size_t)bm * 256;
    #pragma unroll
    for (int i = 0; i < 8; ++i) {
        int u = i * 256 + tid;
        short8v v = *(const short8v*)(Ag + (size_t)u * 8);
        *(short8v*)&As[u >> 5][(u & 31) * 8] = v;
    }
    __syncthreads();

    const unsigned short* bhb = Bpkh + (size_t)w * 16384 + l * 8;

    f32x4 acc[4][4];
    #pragma unroll
    for (int i = 0; i < 4; ++i)
        #pragma unroll
        for (int j = 0; j < 4; ++j) acc[i][j] = (f32x4){0.f, 0.f, 0.f, 0.f};

    #pragma unroll
    for (int ks = 0; ks < 8; ++ks) {
        short8v ah[4], bh[4];
        #pragma unroll
        for (int mf = 0; mf < 4; ++mf)
            ah[mf] = *(const short8v*)&As[mf * 16 + rl][ks * 32 + ql * 8];
        #pragma unroll
        for (int nf = 0; nf < 4; ++nf)
            bh[nf] = *(const short8v*)(bhb + nf * 4096 + ks * 512);
        #pragma unroll
        for (int mf = 0; mf < 4; ++mf)
            #pragma unroll
            for (int nf = 0; nf < 4; ++nf)
                acc[mf][nf] = __builtin_amdgcn_mfma_f32_16x16x32_bf16(ah[mf], bh[nf], acc[mf][nf], 0, 0, 0);
    }

    #pragma unroll
    for (int mf = 0; mf < 4; ++mf) {
        int row0 = bm + mf * 16 + ql * 4;
        #pragma unroll
        for (int nf = 0; nf < 4; ++nf) {
            int c = w * 64 + nf * 16 + rl;
            #pragma unroll
            for (int j = 0; j < 4; ++j) {
                int r = row0 + j;
                if (r < M) {
                    float v = acc[mf][nf][j];
                    Cout[(size_t)r * 256 + c] = 1.f - 2.f / (__expf(2.f * v) + 1.f);
                }
            }
        }
    }
}

extern "C" void kernel_launch(void* const* d_in, const int* in_sizes, int n_in,
                              void* d_out, int out_size, void* d_ws, size_t ws_size,
                              hipStream_t stream) {
    const float* ent  = (const float*)d_in[0];
    const float* rel  = (const float*)d_in[1];
    const float* W    = (const float*)d_in[2];
    const float* W_r  = (const float*)d_in[3];
    const float* a    = (const float*)d_in[4];
    const float* nw   = (const float*)d_in[5];
    const int*   srcp = (const int*)d_in[6];
    const int*   ridp = (const int*)d_in[7];
    float* out = (float*)d_out;

    if (ws_size < WS_NEED) return;

    char* ws = (char*)d_ws;
    double* ssrc0 = (double*)(ws + OFF_SSRC0);
    double* sr0   = (double*)(ws + OFF_SR0);
    double* u0    = (double*)(ws + OFF_U0);
    double* v0    = (double*)(ws + OFF_V0);
    float*  SS    = (float*)(ws + OFF_SS);
    float*  SSR   = (float*)(ws + OFF_SSR);
    float*  U8    = (float*)(ws + OFF_U8);
    float*  V8    = (float*)(ws + OFF_V8);
    unsigned short* b1h = (unsigned short*)(ws + OFF_B1H);
    unsigned short* b2h = (unsigned short*)(ws + OFF_B2H);
    unsigned short* b3h = (unsigned short*)(ws + OFF_B3H);
    unsigned short* rpk = (unsigned short*)(ws + OFF_RPK);
    unsigned short* apk = (unsigned short*)(ws + OFF_EAH);
    unsigned short* embbf = (unsigned short*)(ws + OFF_EMBBF);
    unsigned short* relbf = (unsigned short*)(ws + OFF_RELBF);
    unsigned short* napk = apk;   // neigh row-major aliases ent row-major (dead after gemm_hi)

    setup_kernel<<<258, 256, 0, stream>>>(W, W_r, a, nw, U8, u0, V8, v0,
                                          b1h, b2h, b3h);
    ss_kernel<<<2111, 256, 0, stream>>>(ent, rel, U8, u0, V8, v0,
                                        SS, ssrc0, apk, SSR, sr0, rpk);
    gemm_hi<<<790, 256, 0, stream>>>(apk, b1h, embbf, N_ENT, 782,
                                     rpk, b3h, relbf, N_REL);
    node_kernel<<<3125, 256, 0, stream>>>(srcp, ridp, SS, ssrc0, SSR, sr0,
                                          embbf, relbf, napk);
    gemm_out<<<782, 256, 0, stream>>>(napk, b2h, out, N_ENT);
}

// Round 16
// 138.874 us; speedup vs baseline: 1.0884x; 1.0884x over previous
//
#include <hip/hip_runtime.h>
#include <math.h>

#define N_ENT 50000
#define N_REL 500
#define DEG 32
#define TOPK 10
#define H_DIM 256
#define N_HEADS 4
#define HEAD_DIM 64

typedef __attribute__((ext_vector_type(8))) short short8v;
typedef __attribute__((ext_vector_type(4))) float f32x4;

// ---------------- workspace layout (bytes) ----------------
constexpr size_t OFF_SSRC0 = 0;                      // f64 [N_ENT]
constexpr size_t OFF_SR0   = 400000;                 // f64 [N_REL]
constexpr size_t OFF_U0    = 404000;                 // f64 [256]
constexpr size_t OFF_V0    = 406048;                 // f64 [256]
constexpr size_t OFF_SS    = 408096;                 // f32 [N_ENT][8]
constexpr size_t OFF_SSR   = 2008096;                // f32 [N_REL][8]
constexpr size_t OFF_U8    = 2024096;                // f32 [256][8]
constexpr size_t OFF_V8    = 2032288;                // f32 [256][8]
constexpr size_t OFF_B1H   = 2040480;                // bf16 packed 131072 B each
constexpr size_t OFF_B2H   = 2302624;
constexpr size_t OFF_B3H   = 2564768;
constexpr size_t OFF_NPK   = 3089056;                // bf16 row-major neigh [50048][256]
constexpr size_t OFF_EMBBF = 28713632;               // bf16 [N_ENT][256] emb_t (row-major)
constexpr size_t OFF_RELBF = 54313632;               // bf16 [N_REL][256]
constexpr size_t WS_NEED   = 54569632;               // ~52 MB

__device__ __forceinline__ float leaky(float x) { return x >= 0.f ? x : 0.2f * x; }

__device__ __forceinline__ unsigned short bf16_rne(float x) {
    unsigned int u = __float_as_uint(x);
    unsigned int r = u + 0x7fffu + ((u >> 16) & 1u);
    return (unsigned short)(r >> 16);
}
__device__ __forceinline__ float bf2f(unsigned short x) {
    return __uint_as_float((unsigned)x << 16);
}

// B-side MFMA-fragment pack offset
__device__ __forceinline__ size_t pack_off(int row, int d) {
    return ((size_t)(row >> 4) * 8 + (d >> 5)) * 512 +
           (((d >> 3) & 3) * 16 + (row & 15)) * 8 + (d & 7);
}

// ---------------- K0: setup (U/V vectors | B splits) ----------------
__global__ __launch_bounds__(256) void setup_kernel(
    const float* __restrict__ W, const float* __restrict__ W_r,
    const float* __restrict__ a, const float* __restrict__ nw,
    float* __restrict__ U8, double* __restrict__ u0,
    float* __restrict__ V8, double* __restrict__ v0,
    unsigned short* __restrict__ b1h, unsigned short* __restrict__ b2h,
    unsigned short* __restrict__ b3h)
{
    const int bid = blockIdx.x;
    const int tid = threadIdx.x;
    if (bid == 0) {
        int d = tid;
        #pragma unroll
        for (int h = 0; h < N_HEADS; ++h) {
            float ss = 0.f, sd = 0.f;
            #pragma unroll
            for (int e = 0; e < HEAD_DIM; ++e) {
                float w = W[h * 16384 + d * 64 + e];
                ss += w * a[h * 192 + e];
                sd += w * a[h * 192 + 64 + e];
            }
            U8[d * 8 + h] = ss;
            U8[d * 8 + 4 + h] = sd;
        }
        double s0 = 0.0;
        #pragma unroll
        for (int e = 0; e < HEAD_DIM; ++e)
            s0 += (double)W[d * 64 + e] * (double)a[e];
        u0[d] = s0;
    } else if (bid == 1) {
        int d = tid;
        #pragma unroll
        for (int h = 0; h < N_HEADS; ++h) {
            float sv = 0.f;
            #pragma unroll
            for (int e = 0; e < HEAD_DIM; ++e)
                sv += W_r[h * 16384 + d * 64 + e] * a[h * 192 + 128 + e];
            V8[d * 8 + h] = sv;
            V8[d * 8 + 4 + h] = 0.f;
        }
        double s0 = 0.0;
        #pragma unroll
        for (int e = 0; e < HEAD_DIM; ++e)
            s0 += (double)W_r[d * 64 + e] * (double)a[128 + e];
        v0[d] = s0;
    } else {
        int n = bid - 2;
        int k = tid;
        int h = n >> 6, e = n & 63;
        float x1 = W[h * 16384 + k * 64 + e];
        float x2 = nw[k * 256 + n];
        float x3 = W_r[h * 16384 + k * 64 + e];
        size_t off = pack_off(n, k);
        b1h[off] = bf16_rne(x1);
        b2h[off] = bf16_rne(x2);
        b3h[off] = bf16_rne(x3);
    }
}

// ---------------- K1: fused {f32-A MFMA GEMM -> bf16 tables | rank-1 scores} ----------------
// blocks [0,782): ent GEMM -> embbf; [782,790): rel GEMM -> relbf;
// [790,2838): ent scores; [2838,2901): rel scores.
// GEMM A-staging converts f32->bf16 with the same bf16_rne ss used, so embbf/relbf
// are bit-identical to the previous two-kernel pipeline.
__global__ __launch_bounds__(256) void mid_kernel(
    const float* __restrict__ ent, const float* __restrict__ relm,
    const unsigned short* __restrict__ b1h, const unsigned short* __restrict__ b3h,
    unsigned short* __restrict__ embbf, unsigned short* __restrict__ relbf,
    const float* __restrict__ U8, const double* __restrict__ u0,
    const float* __restrict__ V8, const double* __restrict__ v0,
    float* __restrict__ SS, double* __restrict__ ssrc0,
    float* __restrict__ SSR, double* __restrict__ sr0)
{
    __shared__ unsigned short As[64][264];

    const int b = blockIdx.x;
    const int tid = threadIdx.x;
    const int l = tid & 63;
    const int el = l & 31;

    if (b < 790) {
        // ---- GEMM path ----
        const int w = tid >> 6;
        const int rl = l & 15;
        const int ql = l >> 4;

        const bool isent = (b < 782);
        const float* Af = isent ? ent : relm;
        const unsigned short* Bh = isent ? b1h : b3h;
        unsigned short* C = isent ? embbf : relbf;
        const int M = isent ? N_ENT : N_REL;
        const int bm = (isent ? b : (b - 782)) * 64;

        // stage 64x256 tile: f32 global reads, convert to bf16 in LDS
        #pragma unroll
        for (int i = 0; i < 8; ++i) {
            int u = i * 256 + tid;           // unit = 8 f32
            int row = u >> 5;
            int c8 = (u & 31) * 8;
            int grow = min(bm + row, M - 1);
            float4 v1 = *(const float4*)(Af + (size_t)grow * 256 + c8);
            float4 v2 = *(const float4*)(Af + (size_t)grow * 256 + c8 + 4);
            short8v ov;
            ov[0] = (short)bf16_rne(v1.x); ov[1] = (short)bf16_rne(v1.y);
            ov[2] = (short)bf16_rne(v1.z); ov[3] = (short)bf16_rne(v1.w);
            ov[4] = (short)bf16_rne(v2.x); ov[5] = (short)bf16_rne(v2.y);
            ov[6] = (short)bf16_rne(v2.z); ov[7] = (short)bf16_rne(v2.w);
            *(short8v*)&As[row][c8] = ov;
        }
        __syncthreads();

        const unsigned short* bhb = Bh + (size_t)w * 16384 + l * 8;

        f32x4 acc[4][4];
        #pragma unroll
        for (int i = 0; i < 4; ++i)
            #pragma unroll
            for (int j = 0; j < 4; ++j) acc[i][j] = (f32x4){0.f, 0.f, 0.f, 0.f};

        #pragma unroll
        for (int ks = 0; ks < 8; ++ks) {
            short8v ah[4], bh[4];
            #pragma unroll
            for (int mf = 0; mf < 4; ++mf)
                ah[mf] = *(const short8v*)&As[mf * 16 + rl][ks * 32 + ql * 8];
            #pragma unroll
            for (int nf = 0; nf < 4; ++nf)
                bh[nf] = *(const short8v*)(bhb + nf * 4096 + ks * 512);
            #pragma unroll
            for (int mf = 0; mf < 4; ++mf)
                #pragma unroll
                for (int nf = 0; nf < 4; ++nf)
                    acc[mf][nf] = __builtin_amdgcn_mfma_f32_16x16x32_bf16(ah[mf], bh[nf], acc[mf][nf], 0, 0, 0);
        }

        #pragma unroll
        for (int mf = 0; mf < 4; ++mf) {
            int row0 = bm + mf * 16 + ql * 4;
            #pragma unroll
            for (int nf = 0; nf < 4; ++nf) {
                int c = w * 64 + nf * 16 + rl;
                #pragma unroll
                for (int j = 0; j < 4; ++j) {
                    int r = row0 + j;
                    if (r < M)
                        C[(size_t)r * 256 + c] = bf16_rne(acc[mf][nf][j]);
                }
            }
        }
    } else {
        // ---- score path (no bf16 table writes) ----
        const int q2 = l >> 5;
        const bool isent = (b < 2838);
        const float* X = isent ? ent : relm;
        const float* U8v = isent ? U8 : V8;
        const double* u0v = isent ? u0 : v0;
        float* SSout = isent ? SS : SSR;
        double* s0out = isent ? ssrc0 : sr0;
        const int N = isent ? N_ENT : N_REL;
        const int wave0 = isent ? (((b - 790) * 256 + tid) >> 6)
                                : (((b - 2838) * 256 + tid) >> 6);
        const int nwaves = isent ? 8192 : 252;

        float uu[8][8];
        #pragma unroll
        for (int i = 0; i < 8; ++i) {
            float4 a4 = *(const float4*)(U8v + (el * 8 + i) * 8);
            float4 b4 = *(const float4*)(U8v + (el * 8 + i) * 8 + 4);
            uu[i][0] = a4.x; uu[i][1] = a4.y; uu[i][2] = a4.z; uu[i][3] = a4.w;
            uu[i][4] = b4.x; uu[i][5] = b4.y; uu[i][6] = b4.z; uu[i][7] = b4.w;
        }
        double ud[8];
        #pragma unroll
        for (int i = 0; i < 8; ++i) ud[i] = u0v[el * 8 + i];

        const int jout = ((el & 1) << 2) | (el & 2) | ((el >> 2) & 1);
        const int half = N / 2;

        int p = wave0;
        float4 x1, x2;
        if (p < half) {
            int n0 = p * 2 + q2;
            x1 = *(const float4*)(X + (size_t)n0 * 256 + el * 8);
            x2 = *(const float4*)(X + (size_t)n0 * 256 + el * 8 + 4);
        }
        for (; p < half; p += nwaves) {
            const int n = p * 2 + q2;
            const float4 cx1 = x1, cx2 = x2;
            const int np = p + nwaves;
            if (np < half) {
                int n1 = np * 2 + q2;
                x1 = *(const float4*)(X + (size_t)n1 * 256 + el * 8);
                x2 = *(const float4*)(X + (size_t)n1 * 256 + el * 8 + 4);
            }
            float xs[8] = {cx1.x, cx1.y, cx1.z, cx1.w, cx2.x, cx2.y, cx2.z, cx2.w};

            float pj[8] = {0.f, 0.f, 0.f, 0.f, 0.f, 0.f, 0.f, 0.f};
            double pd = 0.0;
            #pragma unroll
            for (int i = 0; i < 8; ++i) {
                #pragma unroll
                for (int j = 0; j < 8; ++j) pj[j] += xs[i] * uu[i][j];
                pd += (double)xs[i] * ud[i];
            }

            const bool b1 = (el & 1);
            float q[4];
            #pragma unroll
            for (int j = 0; j < 4; ++j) {
                float mine = b1 ? pj[j + 4] : pj[j];
                float send = b1 ? pj[j] : pj[j + 4];
                q[j] = mine + __shfl_xor(send, 1);
            }
            const bool b2 = (el & 2);
            float r2[2];
            #pragma unroll
            for (int j = 0; j < 2; ++j) {
                float mine = b2 ? q[j + 2] : q[j];
                float send = b2 ? q[j] : q[j + 2];
                r2[j] = mine + __shfl_xor(send, 2);
            }
            const bool b4 = (el & 4);
            {
                float mine = b4 ? r2[1] : r2[0];
                float send = b4 ? r2[0] : r2[1];
                r2[0] = mine + __shfl_xor(send, 4);
            }
            r2[0] += __shfl_xor(r2[0], 8);
            r2[0] += __shfl_xor(r2[0], 16);

            #pragma unroll
            for (int off = 1; off < 32; off <<= 1) pd += __shfl_xor(pd, off);

            if (el < 8) SSout[(size_t)n * 8 + jout] = r2[0];
            if (el == 0) s0out[n] = pd;
        }
    }
}

// ---------------- K2: fused top-k select + softmax + gather-aggregate ----------------
// (r14 version: known 58.7 us) 32 lanes per node, 8 nodes per block; no barriers;
// rank via LDS broadcast; no-max softmax; fold-reduced sums; 20-deep fenced hoist.
__global__ __launch_bounds__(256, 3) void node_kernel(
    const int* __restrict__ src, const int* __restrict__ relid,
    const float* __restrict__ SS, const double* __restrict__ ssrc0,
    const float* __restrict__ SSR, const double* __restrict__ sr0,
    const unsigned short* __restrict__ emb_bf, const unsigned short* __restrict__ rel_bf,
    unsigned short* __restrict__ napk)
{
    __shared__ double scs[8][33];
    __shared__ unsigned idsS[8][12];
    __shared__ float wtsS[8][10][4];
    __shared__ float sumsS[8][4];

    const int tid = threadIdx.x;
    const int l = tid & 63;
    const int el = l & 31;
    const int hb = l & 32;
    const int nib = tid >> 5;
    const int n = blockIdx.x * 8 + nib;

    const int sd_ = src[n * DEG + el];
    const int rd_ = relid[n * DEG + el];
    const double sc0 = ssrc0[sd_] + sr0[rd_];
    scs[nib][el] = sc0;

    int cnt = 0;
    #pragma unroll
    for (int j = 0; j < DEG; ++j) {
        double sj = scs[nib][j];
        cnt += (sj > sc0 || (sj == sc0 && j < el)) ? 1 : 0;
    }
    const bool sel = (cnt < TOPK);
    const unsigned mask = (unsigned)(__ballot(sel) >> hb);
    const int pos = __popc(mask & ((1u << el) - 1u));

    float ex = 0.f, ey = 0.f, ez = 0.f, ew = 0.f;
    if (sel) {
        float4 ssv = *(const float4*)(SS + (size_t)sd_ * 8);
        float4 srv = *(const float4*)(SSR + (size_t)rd_ * 8);
        float4 sdv = *(const float4*)(SS + (size_t)n * 8 + 4);
        ex = __expf(leaky(ssv.x + sdv.x + srv.x));
        ey = __expf(leaky(ssv.y + sdv.y + srv.y));
        ez = __expf(leaky(ssv.z + sdv.z + srv.z));
        ew = __expf(leaky(ssv.w + sdv.w + srv.w));
        idsS[nib][pos] = (unsigned)sd_ | ((unsigned)rd_ << 16);
        float4 wv; wv.x = ex; wv.y = ey; wv.z = ez; wv.w = ew;
        *(float4*)&wtsS[nib][pos][0] = wv;
    }

    float p0, p1;
    {
        const bool b1 = (el & 1);
        float m0 = b1 ? ez : ex, s0 = b1 ? ex : ez;
        float m1 = b1 ? ew : ey, s1 = b1 ? ey : ew;
        p0 = m0 + __shfl_xor(s0, 1);
        p1 = m1 + __shfl_xor(s1, 1);
    }
    float qsum;
    {
        const bool b2 = (el & 2);
        float m = b2 ? p1 : p0, s = b2 ? p0 : p1;
        qsum = m + __shfl_xor(s, 2);
    }
    qsum += __shfl_xor(qsum, 4);
    qsum += __shfl_xor(qsum, 8);
    qsum += __shfl_xor(qsum, 16);
    if (el < 4) sumsS[nib][((el & 1) << 1) | ((el >> 1) & 1)] = qsum;

    const int h = el >> 3;

    int skA[TOPK], rkA[TOPK];
    #pragma unroll
    for (int k = 0; k < TOPK; ++k) {
        unsigned idk = idsS[nib][k];
        skA[k] = (int)(idk & 0xFFFFu);
        rkA[k] = (int)(idk >> 16);
    }

    short8v ev[TOPK], rv[TOPK];
    #pragma unroll
    for (int k = 0; k < TOPK; ++k)
        ev[k] = *(const short8v*)(emb_bf + (size_t)skA[k] * 256 + el * 8);
    #pragma unroll
    for (int k = 0; k < TOPK; ++k)
        rv[k] = *(const short8v*)(rel_bf + (size_t)rkA[k] * 256 + el * 8);
    asm volatile("s_waitcnt vmcnt(0)" ::: "memory");

    const float rsh = 1.f / sumsS[nib][h];
    float acc[8] = {0.f, 0.f, 0.f, 0.f, 0.f, 0.f, 0.f, 0.f};
    #pragma unroll
    for (int k = 0; k < TOPK; ++k) {
        float w = wtsS[nib][k][h] * rsh;
        #pragma unroll
        for (int j = 0; j < 8; ++j)
            acc[j] += w * (bf2f((unsigned short)ev[k][j]) + bf2f((unsigned short)rv[k][j]));
    }

    short8v ov;
    #pragma unroll
    for (int j = 0; j < 8; ++j) ov[j] = (short)bf16_rne(acc[j]);
    *(short8v*)(napk + (size_t)n * 256 + el * 8) = ov;
}

// ---------------- K3: MFMA GEMM, row-major A staged to LDS, B hi packed, f32 tanh out ----------------
__global__ __launch_bounds__(256, 4) void gemm_out(
    const unsigned short* __restrict__ A, const unsigned short* __restrict__ Bpkh,
    float* __restrict__ Cout, int M)
{
    __shared__ unsigned short As[64][264];

    const int tid = threadIdx.x;
    const int l = tid & 63;
    const int w = tid >> 6;
    const int bm = blockIdx.x * 64;
    const int rl = l & 15;
    const int ql = l >> 4;

    const unsigned short* Ag = A + (size_t)bm * 256;
    #pragma unroll
    for (int i = 0; i < 8; ++i) {
        int u = i * 256 + tid;
        short8v v = *(const short8v*)(Ag + (size_t)u * 8);
        *(short8v*)&As[u >> 5][(u & 31) * 8] = v;
    }
    __syncthreads();

    const unsigned short* bhb = Bpkh + (size_t)w * 16384 + l * 8;

    f32x4 acc[4][4];
    #pragma unroll
    for (int i = 0; i < 4; ++i)
        #pragma unroll
        for (int j = 0; j < 4; ++j) acc[i][j] = (f32x4){0.f, 0.f, 0.f, 0.f};

    #pragma unroll
    for (int ks = 0; ks < 8; ++ks) {
        short8v ah[4], bh[4];
        #pragma unroll
        for (int mf = 0; mf < 4; ++mf)
            ah[mf] = *(const short8v*)&As[mf * 16 + rl][ks * 32 + ql * 8];
        #pragma unroll
        for (int nf = 0; nf < 4; ++nf)
            bh[nf] = *(const short8v*)(bhb + nf * 4096 + ks * 512);
        #pragma unroll
        for (int mf = 0; mf < 4; ++mf)
            #pragma unroll
            for (int nf = 0; nf < 4; ++nf)
                acc[mf][nf] = __builtin_amdgcn_mfma_f32_16x16x32_bf16(ah[mf], bh[nf], acc[mf][nf], 0, 0, 0);
    }

    #pragma unroll
    for (int mf = 0; mf < 4; ++mf) {
        int row0 = bm + mf * 16 + ql * 4;
        #pragma unroll
        for (int nf = 0; nf < 4; ++nf) {
            int c = w * 64 + nf * 16 + rl;
            #pragma unroll
            for (int j = 0; j < 4; ++j) {
                int r = row0 + j;
                if (r < M) {
                    float v = acc[mf][nf][j];
                    Cout[(size_t)r * 256 + c] = 1.f - 2.f / (__expf(2.f * v) + 1.f);
                }
            }
        }
    }
}

extern "C" void kernel_launch(void* const* d_in, const int* in_sizes, int n_in,
                              void* d_out, int out_size, void* d_ws, size_t ws_size,
                              hipStream_t stream) {
    const float* ent  = (const float*)d_in[0];
    const float* rel  = (const float*)d_in[1];
    const float* W    = (const float*)d_in[2];
    const float* W_r  = (const float*)d_in[3];
    const float* a    = (const float*)d_in[4];
    const float* nw   = (const float*)d_in[5];
    const int*   srcp = (const int*)d_in[6];
    const int*   ridp = (const int*)d_in[7];
    float* out = (float*)d_out;

    if (ws_size < WS_NEED) return;

    char* ws = (char*)d_ws;
    double* ssrc0 = (double*)(ws + OFF_SSRC0);
    double* sr0   = (double*)(ws + OFF_SR0);
    double* u0    = (double*)(ws + OFF_U0);
    double* v0    = (double*)(ws + OFF_V0);
    float*  SS    = (float*)(ws + OFF_SS);
    float*  SSR   = (float*)(ws + OFF_SSR);
    float*  U8    = (float*)(ws + OFF_U8);
    float*  V8    = (float*)(ws + OFF_V8);
    unsigned short* b1h = (unsigned short*)(ws + OFF_B1H);
    unsigned short* b2h = (unsigned short*)(ws + OFF_B2H);
    unsigned short* b3h = (unsigned short*)(ws + OFF_B3H);
    unsigned short* napk = (unsigned short*)(ws + OFF_NPK);
    unsigned short* embbf = (unsigned short*)(ws + OFF_EMBBF);
    unsigned short* relbf = (unsigned short*)(ws + OFF_RELBF);

    setup_kernel<<<258, 256, 0, stream>>>(W, W_r, a, nw, U8, u0, V8, v0,
                                          b1h, b2h, b3h);
    mid_kernel<<<2901, 256, 0, stream>>>(ent, rel, b1h, b3h, embbf, relbf,
                                         U8, u0, V8, v0, SS, ssrc0, SSR, sr0);
    node_kernel<<<6250, 256, 0, stream>>>(srcp, ridp, SS, ssrc0, SSR, sr0,
                                          embbf, relbf, napk);
    gemm_out<<<782, 256, 0, stream>>>(napk, b2h, out, N_ENT);
}

// Round 17
// 125.391 us; speedup vs baseline: 1.2054x; 1.1075x over previous
//
#include <hip/hip_runtime.h>
#include <math.h>

#define N_ENT 50000
#define N_REL 500
#define DEG 32
#define TOPK 10
#define H_DIM 256
#define N_HEADS 4
#define HEAD_DIM 64

typedef __attribute__((ext_vector_type(8))) short short8v;
typedef __attribute__((ext_vector_type(4))) float f32x4;

// ---------------- workspace layout (bytes) ----------------
constexpr size_t OFF_SSRC0 = 0;                      // f64 [N_ENT]
constexpr size_t OFF_SR0   = 400000;                 // f64 [N_REL]
constexpr size_t OFF_U0    = 404000;                 // f64 [256]
constexpr size_t OFF_V0    = 406048;                 // f64 [256]
constexpr size_t OFF_SS    = 408096;                 // f32 [N_ENT][8]
constexpr size_t OFF_SSR   = 2008096;                // f32 [N_REL][8]
constexpr size_t OFF_U8    = 2024096;                // f32 [256][8]
constexpr size_t OFF_V8    = 2032288;                // f32 [256][8]
constexpr size_t OFF_B1H   = 2040480;                // bf16 packed 131072 B each
constexpr size_t OFF_B2H   = 2302624;
constexpr size_t OFF_B3H   = 2564768;
constexpr size_t OFF_NPK   = 3089056;                // bf16 row-major neigh [50048][256]
constexpr size_t OFF_EMBBF = 28713632;               // bf16 [N_ENT][256] emb_t (row-major)
constexpr size_t OFF_RELBF = 54313632;               // bf16 [N_REL][256]
constexpr size_t WS_NEED   = 54569632;               // ~52 MB

__device__ __forceinline__ float leaky(float x) { return x >= 0.f ? x : 0.2f * x; }

__device__ __forceinline__ unsigned short bf16_rne(float x) {
    unsigned int u = __float_as_uint(x);
    unsigned int r = u + 0x7fffu + ((u >> 16) & 1u);
    return (unsigned short)(r >> 16);
}
__device__ __forceinline__ float bf2f(unsigned short x) {
    return __uint_as_float((unsigned)x << 16);
}

// B-side MFMA-fragment pack offset
__device__ __forceinline__ size_t pack_off(int row, int d) {
    return ((size_t)(row >> 4) * 8 + (d >> 5)) * 512 +
           (((d >> 3) & 3) * 16 + (row & 15)) * 8 + (d & 7);
}

// ---------------- K0: setup (U/V vectors | B splits) ----------------
__global__ __launch_bounds__(256) void setup_kernel(
    const float* __restrict__ W, const float* __restrict__ W_r,
    const float* __restrict__ a, const float* __restrict__ nw,
    float* __restrict__ U8, double* __restrict__ u0,
    float* __restrict__ V8, double* __restrict__ v0,
    unsigned short* __restrict__ b1h, unsigned short* __restrict__ b2h,
    unsigned short* __restrict__ b3h)
{
    const int bid = blockIdx.x;
    const int tid = threadIdx.x;
    if (bid == 0) {
        int d = tid;
        #pragma unroll
        for (int h = 0; h < N_HEADS; ++h) {
            float ss = 0.f, sd = 0.f;
            #pragma unroll
            for (int e = 0; e < HEAD_DIM; ++e) {
                float w = W[h * 16384 + d * 64 + e];
                ss += w * a[h * 192 + e];
                sd += w * a[h * 192 + 64 + e];
            }
            U8[d * 8 + h] = ss;
            U8[d * 8 + 4 + h] = sd;
        }
        double s0 = 0.0;
        #pragma unroll
        for (int e = 0; e < HEAD_DIM; ++e)
            s0 += (double)W[d * 64 + e] * (double)a[e];
        u0[d] = s0;
    } else if (bid == 1) {
        int d = tid;
        #pragma unroll
        for (int h = 0; h < N_HEADS; ++h) {
            float sv = 0.f;
            #pragma unroll
            for (int e = 0; e < HEAD_DIM; ++e)
                sv += W_r[h * 16384 + d * 64 + e] * a[h * 192 + 128 + e];
            V8[d * 8 + h] = sv;
            V8[d * 8 + 4 + h] = 0.f;
        }
        double s0 = 0.0;
        #pragma unroll
        for (int e = 0; e < HEAD_DIM; ++e)
            s0 += (double)W_r[d * 64 + e] * (double)a[128 + e];
        v0[d] = s0;
    } else {
        int n = bid - 2;
        int k = tid;
        int h = n >> 6, e = n & 63;
        float x1 = W[h * 16384 + k * 64 + e];
        float x2 = nw[k * 256 + n];
        float x3 = W_r[h * 16384 + k * 64 + e];
        size_t off = pack_off(n, k);
        b1h[off] = bf16_rne(x1);
        b2h[off] = bf16_rne(x2);
        b3h[off] = bf16_rne(x3);
    }
}

// ---------------- K1: single-pass {staging+scores -> MFMA GEMM} ----------------
// blocks [0,782): ent -> embbf + SS/ssrc0; [782,790): rel -> relbf + SSR/sr0.
// Staging lane layout (u&31 == tid&31 == el) matches the old ss_kernel exactly, so
// the score fold-reduction is bit-identical; bf16 conversion identical too.
__global__ __launch_bounds__(256, 3) void mid_kernel(
    const float* __restrict__ ent, const float* __restrict__ relm,
    const unsigned short* __restrict__ b1h, const unsigned short* __restrict__ b3h,
    unsigned short* __restrict__ embbf, unsigned short* __restrict__ relbf,
    const float* __restrict__ U8, const double* __restrict__ u0,
    const float* __restrict__ V8, const double* __restrict__ v0,
    float* __restrict__ SS, double* __restrict__ ssrc0,
    float* __restrict__ SSR, double* __restrict__ sr0)
{
    __shared__ unsigned short As[64][264];

    const int b = blockIdx.x;
    const int tid = threadIdx.x;
    const int l = tid & 63;
    const int el = l & 31;
    const int w = tid >> 6;
    const int rl = l & 15;
    const int ql = l >> 4;

    const bool isent = (b < 782);
    const float* Af = isent ? ent : relm;
    const unsigned short* Bh = isent ? b1h : b3h;
    unsigned short* C = isent ? embbf : relbf;
    const float* U8v = isent ? U8 : V8;
    const double* u0v = isent ? u0 : v0;
    float* SSout = isent ? SS : SSR;
    double* s0out = isent ? ssrc0 : sr0;
    const int M = isent ? N_ENT : N_REL;
    const int bm = (isent ? b : (b - 782)) * 64;

    // this lane's U slice (same layout as old ss_kernel)
    float uu[8][8];
    #pragma unroll
    for (int i = 0; i < 8; ++i) {
        float4 a4 = *(const float4*)(U8v + (el * 8 + i) * 8);
        float4 b4 = *(const float4*)(U8v + (el * 8 + i) * 8 + 4);
        uu[i][0] = a4.x; uu[i][1] = a4.y; uu[i][2] = a4.z; uu[i][3] = a4.w;
        uu[i][4] = b4.x; uu[i][5] = b4.y; uu[i][6] = b4.z; uu[i][7] = b4.w;
    }
    double ud[8];
    #pragma unroll
    for (int i = 0; i < 8; ++i) ud[i] = u0v[el * 8 + i];

    const int jout = ((el & 1) << 2) | (el & 2) | ((el >> 2) & 1);

    // ---- phase A: stage f32->bf16 into LDS + compute scores per row ----
    #pragma unroll
    for (int i = 0; i < 8; ++i) {
        const int row = i * 8 + (tid >> 5);           // u>>5 with u=i*256+tid
        const int grow = min(bm + row, M - 1);
        const float* rp = Af + (size_t)grow * 256 + el * 8;
        float4 v1 = *(const float4*)(rp);
        float4 v2 = *(const float4*)(rp + 4);
        float xs[8] = {v1.x, v1.y, v1.z, v1.w, v2.x, v2.y, v2.z, v2.w};

        short8v ov;
        #pragma unroll
        for (int j = 0; j < 8; ++j) ov[j] = (short)bf16_rne(xs[j]);
        *(short8v*)&As[row][el * 8] = ov;

        float pj[8] = {0.f, 0.f, 0.f, 0.f, 0.f, 0.f, 0.f, 0.f};
        double pd = 0.0;
        #pragma unroll
        for (int ii = 0; ii < 8; ++ii) {
            #pragma unroll
            for (int j = 0; j < 8; ++j) pj[j] += xs[ii] * uu[ii][j];
            pd += (double)xs[ii] * ud[ii];
        }

        const bool b1 = (el & 1);
        float q[4];
        #pragma unroll
        for (int j = 0; j < 4; ++j) {
            float mine = b1 ? pj[j + 4] : pj[j];
            float send = b1 ? pj[j] : pj[j + 4];
            q[j] = mine + __shfl_xor(send, 1);
        }
        const bool b2 = (el & 2);
        float r2[2];
        #pragma unroll
        for (int j = 0; j < 2; ++j) {
            float mine = b2 ? q[j + 2] : q[j];
            float send = b2 ? q[j] : q[j + 2];
            r2[j] = mine + __shfl_xor(send, 2);
        }
        const bool b4 = (el & 4);
        {
            float mine = b4 ? r2[1] : r2[0];
            float send = b4 ? r2[0] : r2[1];
            r2[0] = mine + __shfl_xor(send, 4);
        }
        r2[0] += __shfl_xor(r2[0], 8);
        r2[0] += __shfl_xor(r2[0], 16);

        #pragma unroll
        for (int off = 1; off < 32; off <<= 1) pd += __shfl_xor(pd, off);

        if (el < 8) SSout[(size_t)grow * 8 + jout] = r2[0];
        if (el == 0) s0out[grow] = pd;
    }
    __syncthreads();

    // ---- phase B: MFMA GEMM from LDS A-tile ----
    const unsigned short* bhb = Bh + (size_t)w * 16384 + l * 8;

    f32x4 acc[4][4];
    #pragma unroll
    for (int i = 0; i < 4; ++i)
        #pragma unroll
        for (int j = 0; j < 4; ++j) acc[i][j] = (f32x4){0.f, 0.f, 0.f, 0.f};

    #pragma unroll
    for (int ks = 0; ks < 8; ++ks) {
        short8v ah[4], bh[4];
        #pragma unroll
        for (int mf = 0; mf < 4; ++mf)
            ah[mf] = *(const short8v*)&As[mf * 16 + rl][ks * 32 + ql * 8];
        #pragma unroll
        for (int nf = 0; nf < 4; ++nf)
            bh[nf] = *(const short8v*)(bhb + nf * 4096 + ks * 512);
        #pragma unroll
        for (int mf = 0; mf < 4; ++mf)
            #pragma unroll
            for (int nf = 0; nf < 4; ++nf)
                acc[mf][nf] = __builtin_amdgcn_mfma_f32_16x16x32_bf16(ah[mf], bh[nf], acc[mf][nf], 0, 0, 0);
    }

    #pragma unroll
    for (int mf = 0; mf < 4; ++mf) {
        int row0 = bm + mf * 16 + ql * 4;
        #pragma unroll
        for (int nf = 0; nf < 4; ++nf) {
            int c = w * 64 + nf * 16 + rl;
            #pragma unroll
            for (int j = 0; j < 4; ++j) {
                int r = row0 + j;
                if (r < M)
                    C[(size_t)r * 256 + c] = bf16_rne(acc[mf][nf][j]);
            }
        }
    }
}

// ---------------- K2: fused top-k select + softmax + gather-aggregate ----------------
// 32 lanes per node, 8 nodes per block; no barriers; rank via LDS broadcast;
// no-max softmax; fold-reduced sums; 20-deep fenced gather hoist.
__global__ __launch_bounds__(256, 3) void node_kernel(
    const int* __restrict__ src, const int* __restrict__ relid,
    const float* __restrict__ SS, const double* __restrict__ ssrc0,
    const float* __restrict__ SSR, const double* __restrict__ sr0,
    const unsigned short* __restrict__ emb_bf, const unsigned short* __restrict__ rel_bf,
    unsigned short* __restrict__ napk)
{
    __shared__ double scs[8][33];
    __shared__ unsigned idsS[8][12];
    __shared__ float wtsS[8][10][4];
    __shared__ float sumsS[8][4];

    const int tid = threadIdx.x;
    const int l = tid & 63;
    const int el = l & 31;
    const int hb = l & 32;
    const int nib = tid >> 5;
    const int n = blockIdx.x * 8 + nib;

    const int sd_ = src[n * DEG + el];
    const int rd_ = relid[n * DEG + el];
    const double sc0 = ssrc0[sd_] + sr0[rd_];
    scs[nib][el] = sc0;

    int cnt = 0;
    #pragma unroll
    for (int j = 0; j < DEG; ++j) {
        double sj = scs[nib][j];
        cnt += (sj > sc0 || (sj == sc0 && j < el)) ? 1 : 0;
    }
    const bool sel = (cnt < TOPK);
    const unsigned mask = (unsigned)(__ballot(sel) >> hb);
    const int pos = __popc(mask & ((1u << el) - 1u));

    float ex = 0.f, ey = 0.f, ez = 0.f, ew = 0.f;
    if (sel) {
        float4 ssv = *(const float4*)(SS + (size_t)sd_ * 8);
        float4 srv = *(const float4*)(SSR + (size_t)rd_ * 8);
        float4 sdv = *(const float4*)(SS + (size_t)n * 8 + 4);
        ex = __expf(leaky(ssv.x + sdv.x + srv.x));
        ey = __expf(leaky(ssv.y + sdv.y + srv.y));
        ez = __expf(leaky(ssv.z + sdv.z + srv.z));
        ew = __expf(leaky(ssv.w + sdv.w + srv.w));
        idsS[nib][pos] = (unsigned)sd_ | ((unsigned)rd_ << 16);
        float4 wv; wv.x = ex; wv.y = ey; wv.z = ez; wv.w = ew;
        *(float4*)&wtsS[nib][pos][0] = wv;
    }

    float p0, p1;
    {
        const bool b1 = (el & 1);
        float m0 = b1 ? ez : ex, s0 = b1 ? ex : ez;
        float m1 = b1 ? ew : ey, s1 = b1 ? ey : ew;
        p0 = m0 + __shfl_xor(s0, 1);
        p1 = m1 + __shfl_xor(s1, 1);
    }
    float qsum;
    {
        const bool b2 = (el & 2);
        float m = b2 ? p1 : p0, s = b2 ? p0 : p1;
        qsum = m + __shfl_xor(s, 2);
    }
    qsum += __shfl_xor(qsum, 4);
    qsum += __shfl_xor(qsum, 8);
    qsum += __shfl_xor(qsum, 16);
    if (el < 4) sumsS[nib][((el & 1) << 1) | ((el >> 1) & 1)] = qsum;

    const int h = el >> 3;

    int skA[TOPK], rkA[TOPK];
    #pragma unroll
    for (int k = 0; k < TOPK; ++k) {
        unsigned idk = idsS[nib][k];
        skA[k] = (int)(idk & 0xFFFFu);
        rkA[k] = (int)(idk >> 16);
    }

    short8v ev[TOPK], rv[TOPK];
    #pragma unroll
    for (int k = 0; k < TOPK; ++k)
        ev[k] = *(const short8v*)(emb_bf + (size_t)skA[k] * 256 + el * 8);
    #pragma unroll
    for (int k = 0; k < TOPK; ++k)
        rv[k] = *(const short8v*)(rel_bf + (size_t)rkA[k] * 256 + el * 8);
    asm volatile("s_waitcnt vmcnt(0)" ::: "memory");

    const float rsh = 1.f / sumsS[nib][h];
    float acc[8] = {0.f, 0.f, 0.f, 0.f, 0.f, 0.f, 0.f, 0.f};
    #pragma unroll
    for (int k = 0; k < TOPK; ++k) {
        float w = wtsS[nib][k][h] * rsh;
        #pragma unroll
        for (int j = 0; j < 8; ++j)
            acc[j] += w * (bf2f((unsigned short)ev[k][j]) + bf2f((unsigned short)rv[k][j]));
    }

    short8v ov;
    #pragma unroll
    for (int j = 0; j < 8; ++j) ov[j] = (short)bf16_rne(acc[j]);
    *(short8v*)(napk + (size_t)n * 256 + el * 8) = ov;
}

// ---------------- K3: MFMA GEMM, row-major A staged to LDS, B hi packed, f32 tanh out ----------------
__global__ __launch_bounds__(256, 4) void gemm_out(
    const unsigned short* __restrict__ A, const unsigned short* __restrict__ Bpkh,
    float* __restrict__ Cout, int M)
{
    __shared__ unsigned short As[64][264];

    const int tid = threadIdx.x;
    const int l = tid & 63;
    const int w = tid >> 6;
    const int bm = blockIdx.x * 64;
    const int rl = l & 15;
    const int ql = l >> 4;

    const unsigned short* Ag = A + (size_t)bm * 256;
    #pragma unroll
    for (int i = 0; i < 8; ++i) {
        int u = i * 256 + tid;
        short8v v = *(const short8v*)(Ag + (size_t)u * 8);
        *(short8v*)&As[u >> 5][(u & 31) * 8] = v;
    }
    __syncthreads();

    const unsigned short* bhb = Bpkh + (size_t)w * 16384 + l * 8;

    f32x4 acc[4][4];
    #pragma unroll
    for (int i = 0; i < 4; ++i)
        #pragma unroll
        for (int j = 0; j < 4; ++j) acc[i][j] = (f32x4){0.f, 0.f, 0.f, 0.f};

    #pragma unroll
    for (int ks = 0; ks < 8; ++ks) {
        short8v ah[4], bh[4];
        #pragma unroll
        for (int mf = 0; mf < 4; ++mf)
            ah[mf] = *(const short8v*)&As[mf * 16 + rl][ks * 32 + ql * 8];
        #pragma unroll
        for (int nf = 0; nf < 4; ++nf)
            bh[nf] = *(const short8v*)(bhb + nf * 4096 + ks * 512);
        #pragma unroll
        for (int mf = 0; mf < 4; ++mf)
            #pragma unroll
            for (int nf = 0; nf < 4; ++nf)
                acc[mf][nf] = __builtin_amdgcn_mfma_f32_16x16x32_bf16(ah[mf], bh[nf], acc[mf][nf], 0, 0, 0);
    }

    #pragma unroll
    for (int mf = 0; mf < 4; ++mf) {
        int row0 = bm + mf * 16 + ql * 4;
        #pragma unroll
        for (int nf = 0; nf < 4; ++nf) {
            int c = w * 64 + nf * 16 + rl;
            #pragma unroll
            for (int j = 0; j < 4; ++j) {
                int r = row0 + j;
                if (r < M) {
                    float v = acc[mf][nf][j];
                    Cout[(size_t)r * 256 + c] = 1.f - 2.f / (__expf(2.f * v) + 1.f);
                }
            }
        }
    }
}

extern "C" void kernel_launch(void* const* d_in, const int* in_sizes, int n_in,
                              void* d_out, int out_size, void* d_ws, size_t ws_size,
                              hipStream_t stream) {
    const float* ent  = (const float*)d_in[0];
    const float* rel  = (const float*)d_in[1];
    const float* W    = (const float*)d_in[2];
    const float* W_r  = (const float*)d_in[3];
    const float* a    = (const float*)d_in[4];
    const float* nw   = (const float*)d_in[5];
    const int*   srcp = (const int*)d_in[6];
    const int*   ridp = (const int*)d_in[7];
    float* out = (float*)d_out;

    if (ws_size < WS_NEED) return;

    char* ws = (char*)d_ws;
    double* ssrc0 = (double*)(ws + OFF_SSRC0);
    double* sr0   = (double*)(ws + OFF_SR0);
    double* u0    = (double*)(ws + OFF_U0);
    double* v0    = (double*)(ws + OFF_V0);
    float*  SS    = (float*)(ws + OFF_SS);
    float*  SSR   = (float*)(ws + OFF_SSR);
    float*  U8    = (float*)(ws + OFF_U8);
    float*  V8    = (float*)(ws + OFF_V8);
    unsigned short* b1h = (unsigned short*)(ws + OFF_B1H);
    unsigned short* b2h = (unsigned short*)(ws + OFF_B2H);
    unsigned short* b3h = (unsigned short*)(ws + OFF_B3H);
    unsigned short* napk = (unsigned short*)(ws + OFF_NPK);
    unsigned short* embbf = (unsigned short*)(ws + OFF_EMBBF);
    unsigned short* relbf = (unsigned short*)(ws + OFF_RELBF);

    setup_kernel<<<258, 256, 0, stream>>>(W, W_r, a, nw, U8, u0, V8, v0,
                                          b1h, b2h, b3h);
    mid_kernel<<<790, 256, 0, stream>>>(ent, rel, b1h, b3h, embbf, relbf,
                                        U8, u0, V8, v0, SS, ssrc0, SSR, sr0);
    node_kernel<<<6250, 256, 0, stream>>>(srcp, ridp, SS, ssrc0, SSR, sr0,
                                          embbf, relbf, napk);
    gemm_out<<<782, 256, 0, stream>>>(napk, b2h, out, N_ENT);
}